// Round 5
// baseline (1601.903 us; speedup 1.0000x reference)
//
#include <hip/hip_runtime.h>

// out[n,k] = softmax_k( 2*x_n.c_k - ||c_k||^2 )   (x_sqr cancels in softmax)
// 3-product bf16 split GEMM (logical K = 3*512 = 1536), 256x256 tiles,
// per K-tile: barrier A -> stage(next) -> counted vmcnt(8) -> barrier B ->
// straight-line body (24 ds_read_b128 + 64 MFMA, compiler-scheduled).
// Lane-constant XOR bank swizzle, f16-exp compressed logits.

typedef __attribute__((ext_vector_type(8))) __bf16 bf16x8;
typedef __attribute__((ext_vector_type(4))) float f32x4;

typedef __attribute__((address_space(1))) const void global_cvoid;
typedef __attribute__((address_space(3))) void lds_void;

__device__ inline unsigned short f32_to_bf16_rne(float f) {
    unsigned int u = __float_as_uint(f);
    unsigned int r = u + 0x7FFFu + ((u >> 16) & 1u);
    return (unsigned short)(r >> 16);
}
__device__ inline float bf16u_to_f32(unsigned short h) {
    return __uint_as_float(((unsigned int)h) << 16);
}

// ---------------- prep: fp32 -> bf16 hi/lo split ----------------
__global__ void split_kernel(const float* __restrict__ in,
                             unsigned short* __restrict__ hi,
                             unsigned short* __restrict__ lo, int n4) {
    int i = blockIdx.x * blockDim.x + threadIdx.x;
    int stride = gridDim.x * blockDim.x;
    for (; i < n4; i += stride) {
        float4 v = reinterpret_cast<const float4*>(in)[i];
        float vv[4] = {v.x, v.y, v.z, v.w};
        ushort4 hv, lv;
        unsigned short h[4], l[4];
#pragma unroll
        for (int j = 0; j < 4; ++j) {
            h[j] = f32_to_bf16_rne(vv[j]);
            float r = vv[j] - bf16u_to_f32(h[j]);
            l[j] = f32_to_bf16_rne(r);
        }
        hv.x = h[0]; hv.y = h[1]; hv.z = h[2]; hv.w = h[3];
        lv.x = l[0]; lv.y = l[1]; lv.z = l[2]; lv.w = l[3];
        reinterpret_cast<ushort4*>(hi)[i] = hv;
        reinterpret_cast<ushort4*>(lo)[i] = lv;
    }
}

// ---------------- prep: codebook row squared norms ----------------
__global__ void rowsq_kernel(const float* __restrict__ cb, float* __restrict__ out) {
    int row = blockIdx.x * 4 + (threadIdx.x >> 6);
    int lane = threadIdx.x & 63;
    const float4* p = reinterpret_cast<const float4*>(cb + (size_t)row * 512);
    float4 a = p[lane];
    float4 b = p[lane + 64];
    float s = a.x * a.x + a.y * a.y + a.z * a.z + a.w * a.w +
              b.x * b.x + b.y * b.y + b.z * b.z + b.w * b.w;
#pragma unroll
    for (int o = 32; o >= 1; o >>= 1) s += __shfl_xor(s, o);
    if (lane == 0) out[row] = s;
}

// ---------------- GEMM 256x256 ----------------
// Grid 4096 (128 bm x 32 bn, bijective XCD swizzle), 512 threads = 8 waves (2x4).
// LDS: lds[buf][mat A/B][kk][256 rows x 32 k bf16] = 128 KiB. 24 K-tiles of BK=64.
// Swizzle: 16B-slot col c_phys = c_log ^ ((row>>2)&3)  (lane-constant on read side).

#define ST_ALL(tt_, b_)                                                                 \
    { int prod_ = (tt_) >> 3, ch_ = (tt_) & 7;                                          \
      const unsigned short* Abase_ = (prod_ < 2 ? Ah : Al) + arow0 + ch_ * 64;          \
      const unsigned short* Bbase_ = (prod_ == 1 ? Bl : Bh) + brow0 + ch_ * 64;         \
      _Pragma("unroll") for (int kk_ = 0; kk_ < 2; ++kk_) {                             \
        _Pragma("unroll") for (int j = 0; j < 2; ++j) {                                 \
          __builtin_amdgcn_global_load_lds((global_cvoid*)(Abase_ + kk_ * 32 + goff[j]),\
              (lds_void*)&lds[b_][0][kk_][sl8[j]], 16, 0, 0);                           \
          __builtin_amdgcn_global_load_lds((global_cvoid*)(Bbase_ + kk_ * 32 + goff[j]),\
              (lds_void*)&lds[b_][1][kk_][sl8[j]], 16, 0, 0);                           \
        } } }

template <int F16>
__global__ __launch_bounds__(512, 2) void gemm_kernel(
    const unsigned short* __restrict__ Ah, const unsigned short* __restrict__ Al,
    const unsigned short* __restrict__ Bh, const unsigned short* __restrict__ Bl,
    const float* __restrict__ cbq, float* __restrict__ outf,
    unsigned short* __restrict__ p16, float* __restrict__ max_part,
    float* __restrict__ sum_part) {
    __shared__ __align__(16) unsigned short lds[2][2][2][8192];  // 128 KiB

    const int t = threadIdx.x;
    const int lane = t & 63;
    const int w = t >> 6;
    const int wm = w >> 2, wn = w & 3;  // 2 x 4 waves, each owns 128x64 output
    const int fr = lane & 15, fg = lane >> 4;

    int bid = blockIdx.x;
    int swz = (bid & 7) * 512 + (bid >> 3);  // 4096 % 8 == 0 -> bijective
    const int bm = swz >> 5, bn = swz & 31;
    const int row0 = bm * 256, col0 = bn * 256;
    const size_t arow0 = (size_t)row0 * 512;
    const size_t brow0 = (size_t)col0 * 512;

    // read-side: phys 16B-slot = row*4 + (col ^ ((row>>2)&3)); row bases are
    // multiples of 16 so the XOR term is lane-constant:
    const int xsl = fg ^ ((fr >> 2) & 3);
    const int a_slot = (wm * 128 + fr) * 4 + xsl;  // + (mq*4+m)*64
    const int b_slot = (wn * 64 + fr) * 4 + xsl;   // + n*64

    // staging: thread t, load j covers phys slot s = j*512 + t of a [256][32] unit
    int goff[2], sl8[2];
#pragma unroll
    for (int j = 0; j < 2; ++j) {
        int s = j * 512 + t;
        int r_ = s >> 2, cp_ = s & 3;
        int cl_ = cp_ ^ ((r_ >> 2) & 3);
        goff[j] = r_ * 512 + cl_ * 8;
        sl8[j] = s * 8;
    }

    f32x4 acc[8][4] = {};

    // prologue: stage tile 0 into buf 0
    ST_ALL(0, 0);

    for (int tt = 0; tt < 24; ++tt) {
        const int cur = tt & 1;
        // barrier A: all waves done reading buf[cur^1] (body tt-1) -> safe to overwrite
        __builtin_amdgcn_sched_barrier(0);
        __builtin_amdgcn_s_barrier();
        __builtin_amdgcn_sched_barrier(0);
        if (tt < 23) {
            ST_ALL(tt + 1, cur ^ 1);
            asm volatile("s_waitcnt vmcnt(8)" ::: "memory");  // MY tile-tt loads landed
        } else {
            asm volatile("s_waitcnt vmcnt(0)" ::: "memory");
        }
        __builtin_amdgcn_sched_barrier(0);
        // barrier B: publishes "ALL waves' tile-tt loads landed" (vmcnt is per-wave)
        __builtin_amdgcn_s_barrier();
        __builtin_amdgcn_sched_barrier(0);
        // straight-line tile body: 24 ds_read_b128 + 64 MFMA, compiler-scheduled
#pragma unroll
        for (int kk = 0; kk < 2; ++kk) {
            bf16x8 bfr[4], afrA[4], afrB[4];
#pragma unroll
            for (int n = 0; n < 4; ++n)
                bfr[n] = *(const bf16x8*)&lds[cur][1][kk][(b_slot + n * 64) * 8];
#pragma unroll
            for (int m = 0; m < 4; ++m)
                afrA[m] = *(const bf16x8*)&lds[cur][0][kk][(a_slot + m * 64) * 8];
#pragma unroll
            for (int m = 0; m < 4; ++m)
                afrB[m] = *(const bf16x8*)&lds[cur][0][kk][(a_slot + (m + 4) * 64) * 8];
#pragma unroll
            for (int m = 0; m < 4; ++m)
#pragma unroll
                for (int n = 0; n < 4; ++n)
                    acc[m][n] = __builtin_amdgcn_mfma_f32_16x16x32_bf16(
                        afrA[m], bfr[n], acc[m][n], 0, 0, 0);
#pragma unroll
            for (int m = 0; m < 4; ++m)
#pragma unroll
                for (int n = 0; n < 4; ++n)
                    acc[4 + m][n] = __builtin_amdgcn_mfma_f32_16x16x32_bf16(
                        afrB[m], bfr[n], acc[4 + m][n], 0, 0, 0);
        }
    }

    // ---- epilogue ----
    float* redm = (float*)&lds[0][0][0][0];  // reuse buf0 region after loop
    float* reds = redm + 1024;

    float cq[4];
#pragma unroll
    for (int n = 0; n < 4; ++n) cq[n] = cbq[col0 + wn * 64 + n * 16 + fr];
#pragma unroll
    for (int m = 0; m < 8; ++m)
#pragma unroll
        for (int n = 0; n < 4; ++n)
#pragma unroll
            for (int r = 0; r < 4; ++r)
                acc[m][n][r] = 2.0f * acc[m][n][r] - cq[n];

    float rmx[8][4];
#pragma unroll
    for (int m = 0; m < 8; ++m)
#pragma unroll
        for (int r = 0; r < 4; ++r) {
            float v = fmaxf(fmaxf(acc[m][0][r], acc[m][1][r]),
                            fmaxf(acc[m][2][r], acc[m][3][r]));
#pragma unroll
            for (int o = 1; o < 16; o <<= 1) v = fmaxf(v, __shfl_xor(v, o));
            rmx[m][r] = v;
        }
    __syncthreads();  // all waves out of the K-loop before LDS reuse
    if (fr == 0) {
#pragma unroll
        for (int m = 0; m < 8; ++m)
#pragma unroll
            for (int r = 0; r < 4; ++r)
                redm[wn * 256 + wm * 128 + m * 16 + fg * 4 + r] = rmx[m][r];
    }
    __syncthreads();
#pragma unroll
    for (int m = 0; m < 8; ++m)
#pragma unroll
        for (int r = 0; r < 4; ++r) {
            int row = wm * 128 + m * 16 + fg * 4 + r;
            rmx[m][r] = fmaxf(fmaxf(redm[row], redm[256 + row]),
                              fmaxf(redm[512 + row], redm[768 + row]));
        }
#pragma unroll
    for (int m = 0; m < 8; ++m)
#pragma unroll
        for (int r = 0; r < 4; ++r) {
            float s = 0.f;
#pragma unroll
            for (int n = 0; n < 4; ++n) s += __expf(acc[m][n][r] - rmx[m][r]);
#pragma unroll
            for (int o = 1; o < 16; o <<= 1) s += __shfl_xor(s, o);
            if (fr == 0) reds[wn * 256 + wm * 128 + m * 16 + fg * 4 + r] = s;
        }
    __syncthreads();
    if (wn == 0 && fr == 0) {
#pragma unroll
        for (int m = 0; m < 8; ++m)
#pragma unroll
            for (int r = 0; r < 4; ++r) {
                int row = wm * 128 + m * 16 + fg * 4 + r;
                size_t gr = (size_t)(row0 + row);
                max_part[gr * 32 + bn] = rmx[m][r];
                sum_part[gr * 32 + bn] =
                    reds[row] + reds[256 + row] + reds[512 + row] + reds[768 + row];
            }
    }
#pragma unroll
    for (int m = 0; m < 8; ++m)
#pragma unroll
        for (int n = 0; n < 4; ++n)
#pragma unroll
            for (int r = 0; r < 4; ++r) {
                size_t gr = (size_t)(row0 + wm * 128 + m * 16 + fg * 4 + r);
                size_t gi = gr * 8192 + col0 + wn * 64 + n * 16 + fr;
                if constexpr (F16) {
                    union { _Float16 h; unsigned short u; } cv;
                    cv.h = (_Float16)__expf(acc[m][n][r] - rmx[m][r]);
                    p16[gi] = cv.u;
                } else {
                    outf[gi] = acc[m][n][r];
                }
            }
}

// ---------------- combine partials over 32 col-blocks per row ----------------
__global__ void combine_kernel(const float* __restrict__ max_part,
                               const float* __restrict__ sum_part,
                               float* __restrict__ row_m, float* __restrict__ row_is,
                               float* __restrict__ scale, int do_scale) {
    int row = blockIdx.x * 8 + (threadIdx.x >> 5);
    int l = threadIdx.x & 31;
    size_t off = (size_t)row * 32 + l;
    float m = max_part[off];
    float s = sum_part[off];
    float gm = m;
#pragma unroll
    for (int o = 16; o >= 1; o >>= 1) gm = fmaxf(gm, __shfl_xor(gm, o, 32));
    float c = s * __expf(m - gm);
#pragma unroll
    for (int o = 16; o >= 1; o >>= 1) c += __shfl_xor(c, o, 32);
    float inv = 1.0f / c;
    if (do_scale) scale[off] = __expf(m - gm) * inv;
    if (l == 0) {
        row_m[row] = gm;
        row_is[row] = inv;
    }
}

// ---------------- normalize: f32-logit path ----------------
__global__ void norm_kernel(float* __restrict__ out, const float* __restrict__ row_m,
                            const float* __restrict__ row_is) {
    size_t i = (size_t)blockIdx.x * blockDim.x + threadIdx.x;
    size_t stride = (size_t)gridDim.x * blockDim.x;
    const size_t n4 = 268435456ull / 4;
    float4* p = reinterpret_cast<float4*>(out);
    for (; i < n4; i += stride) {
        int row = (int)(i >> 11);
        float m = row_m[row];
        float is = row_is[row];
        float4 v = p[i];
        v.x = __expf(v.x - m) * is;
        v.y = __expf(v.y - m) * is;
        v.z = __expf(v.z - m) * is;
        v.w = __expf(v.w - m) * is;
        p[i] = v;
    }
}

// ---------------- normalize: f16-exp path ----------------
__global__ void norm_f16_kernel(const unsigned short* __restrict__ p16,
                                const float* __restrict__ scale,
                                float* __restrict__ out) {
    size_t i = (size_t)blockIdx.x * blockDim.x + threadIdx.x;  // 8-elem group id
    size_t stride = (size_t)gridDim.x * blockDim.x;
    const size_t ng = 268435456ull / 8;
    const uint4* src = reinterpret_cast<const uint4*>(p16);
    float4* dst = reinterpret_cast<float4*>(out);
    for (; i < ng; i += stride) {
        int row = (int)(i >> 10);        // 1024 groups per row
        int bn = (int)((i >> 5) & 31);   // 32 groups per 256-col block
        float s = scale[(size_t)row * 32 + bn];
        union { uint4 u; _Float16 h[8]; } cv;
        cv.u = src[i];
        float4 o1, o2;
        o1.x = (float)cv.h[0] * s; o1.y = (float)cv.h[1] * s;
        o1.z = (float)cv.h[2] * s; o1.w = (float)cv.h[3] * s;
        o2.x = (float)cv.h[4] * s; o2.y = (float)cv.h[5] * s;
        o2.z = (float)cv.h[6] * s; o2.w = (float)cv.h[7] * s;
        dst[i * 2] = o1;
        dst[i * 2 + 1] = o2;
    }
}

extern "C" void kernel_launch(void* const* d_in, const int* in_sizes, int n_in,
                              void* d_out, int out_size, void* d_ws, size_t ws_size,
                              hipStream_t stream) {
    const float* x = (const float*)d_in[0];   // [32768,512]
    const float* cb = (const float*)d_in[1];  // [8192,512]
    float* out = (float*)d_out;               // [32768,8192]
    char* ws = (char*)d_ws;

    unsigned short* Xh = (unsigned short*)(ws);                 // 33,554,432
    unsigned short* Xl = (unsigned short*)(ws + 33554432ull);   // 33,554,432
    unsigned short* Ch = (unsigned short*)(ws + 67108864ull);   // 8,388,608
    unsigned short* Cl = (unsigned short*)(ws + 75497472ull);   // 8,388,608
    float* cbq       = (float*)(ws + 83886080ull);              // 32,768
    float* max_part  = (float*)(ws + 83918848ull);              // 4,194,304
    float* sum_part  = (float*)(ws + 88113152ull);              // 4,194,304
    float* row_m     = (float*)(ws + 92307456ull);              // 131,072
    float* row_is    = (float*)(ws + 92438528ull);              // 131,072
    float* scale     = (float*)(ws + 92569600ull);              // 4,194,304
    unsigned short* p16 = (unsigned short*)(ws + 96763904ull);  // 536,870,912 -> 633,634,816

    const bool f16path = (ws_size >= 633634816ull);

    split_kernel<<<2048, 256, 0, stream>>>(x, Xh, Xl, 32768 * 512 / 4);
    split_kernel<<<1024, 256, 0, stream>>>(cb, Ch, Cl, 8192 * 512 / 4);
    rowsq_kernel<<<2048, 256, 0, stream>>>(cb, cbq);
    if (f16path) {
        gemm_kernel<1><<<4096, 512, 0, stream>>>(Xh, Xl, Ch, Cl, cbq, out, p16,
                                                 max_part, sum_part);
        combine_kernel<<<4096, 256, 0, stream>>>(max_part, sum_part, row_m, row_is,
                                                 scale, 1);
        norm_f16_kernel<<<4096, 256, 0, stream>>>(p16, scale, out);
    } else {
        gemm_kernel<0><<<4096, 512, 0, stream>>>(Xh, Xl, Ch, Cl, cbq, out, p16,
                                                 max_part, sum_part);
        combine_kernel<<<4096, 256, 0, stream>>>(max_part, sum_part, row_m, row_is,
                                                 scale, 0);
        norm_kernel<<<4096, 256, 0, stream>>>(out, row_m, row_is);
    }
}

// Round 6
// 1406.249 us; speedup vs baseline: 1.1391x; 1.1391x over previous
//
#include <hip/hip_runtime.h>

// out[n,k] = softmax_k( 2*x_n.c_k - ||c_k||^2 )   (x_sqr cancels in softmax)
// 3-product bf16 split GEMM (logical K = 3*512 = 1536), 256x256 tiles,
// 4 phases/K-tile (16 MFMA each), k-slice stage units, counted vmcnt(4)
// fused into asm barriers (memory-clobber = the collective-gate fence),
// NO sched_barrier(0) (m141), lane-constant XOR bank swizzle, f16-exp logits.

typedef __attribute__((ext_vector_type(8))) __bf16 bf16x8;
typedef __attribute__((ext_vector_type(4))) float f32x4;

typedef __attribute__((address_space(1))) const void global_cvoid;
typedef __attribute__((address_space(3))) void lds_void;

__device__ inline unsigned short f32_to_bf16_rne(float f) {
    unsigned int u = __float_as_uint(f);
    unsigned int r = u + 0x7FFFu + ((u >> 16) & 1u);
    return (unsigned short)(r >> 16);
}
__device__ inline float bf16u_to_f32(unsigned short h) {
    return __uint_as_float(((unsigned int)h) << 16);
}

// ---------------- prep: fp32 -> bf16 hi/lo split ----------------
__global__ void split_kernel(const float* __restrict__ in,
                             unsigned short* __restrict__ hi,
                             unsigned short* __restrict__ lo, int n4) {
    int i = blockIdx.x * blockDim.x + threadIdx.x;
    int stride = gridDim.x * blockDim.x;
    for (; i < n4; i += stride) {
        float4 v = reinterpret_cast<const float4*>(in)[i];
        float vv[4] = {v.x, v.y, v.z, v.w};
        ushort4 hv, lv;
        unsigned short h[4], l[4];
#pragma unroll
        for (int j = 0; j < 4; ++j) {
            h[j] = f32_to_bf16_rne(vv[j]);
            float r = vv[j] - bf16u_to_f32(h[j]);
            l[j] = f32_to_bf16_rne(r);
        }
        hv.x = h[0]; hv.y = h[1]; hv.z = h[2]; hv.w = h[3];
        lv.x = l[0]; lv.y = l[1]; lv.z = l[2]; lv.w = l[3];
        reinterpret_cast<ushort4*>(hi)[i] = hv;
        reinterpret_cast<ushort4*>(lo)[i] = lv;
    }
}

// ---------------- prep: codebook row squared norms ----------------
__global__ void rowsq_kernel(const float* __restrict__ cb, float* __restrict__ out) {
    int row = blockIdx.x * 4 + (threadIdx.x >> 6);
    int lane = threadIdx.x & 63;
    const float4* p = reinterpret_cast<const float4*>(cb + (size_t)row * 512);
    float4 a = p[lane];
    float4 b = p[lane + 64];
    float s = a.x * a.x + a.y * a.y + a.z * a.z + a.w * a.w +
              b.x * b.x + b.y * b.y + b.z * b.z + b.w * b.w;
#pragma unroll
    for (int o = 32; o >= 1; o >>= 1) s += __shfl_xor(s, o);
    if (lane == 0) out[row] = s;
}

// ---------------- GEMM 256x256 ----------------
// Grid 4096 (128 bm x 32 bn, bijective XCD swizzle), 512 threads = 8 waves (2x4).
// LDS: lds[buf][mat A/B][kk][256 rows x 32 k bf16] = 128 KiB. 24 K-tiles of BK=64.
// Swizzle: 16B-slot col c_phys = c_log ^ ((row>>2)&3)  (lane-constant on read side).

#define RD_A(mq_, kk_, b_)                                                        \
    { _Pragma("unroll") for (int m = 0; m < 4; ++m)                               \
        afr[m] = *(const bf16x8*)&lds[b_][0][kk_][(a_slot + ((mq_)*4 + m) * 64) * 8]; }

#define RD_B(kk_, b_)                                                             \
    { _Pragma("unroll") for (int n = 0; n < 4; ++n)                               \
        bfr[n] = *(const bf16x8*)&lds[b_][1][kk_][(b_slot + n * 64) * 8]; }

#define ST(mat_, kk_, b_, tt_)                                                    \
    { int prod_ = (tt_) >> 3, ch_ = (tt_) & 7;                                    \
      const unsigned short* bse_;                                                 \
      if ((mat_) == 0) bse_ = (prod_ < 2 ? Ah : Al) + arow0;                      \
      else             bse_ = (prod_ == 1 ? Bl : Bh) + brow0;                     \
      bse_ += ch_ * 64 + (kk_) * 32;                                              \
      _Pragma("unroll") for (int j = 0; j < 2; ++j)                               \
          __builtin_amdgcn_global_load_lds((global_cvoid*)(bse_ + goff[j]),       \
              (lds_void*)&lds[b_][mat_][kk_][sl8[j]], 16, 0, 0);                  \
    }

#define MM(mq_)                                                                   \
    { _Pragma("unroll") for (int m = 0; m < 4; ++m)                               \
      _Pragma("unroll") for (int n = 0; n < 4; ++n)                               \
          acc[(mq_) * 4 + m][n] = __builtin_amdgcn_mfma_f32_16x16x32_bf16(        \
              afr[m], bfr[n], acc[(mq_) * 4 + m][n], 0, 0, 0); }

// MID: all waves arrived + my ds_reads complete (memory clobber also pins ST order)
#define MIDSYNC()                                                                 \
    { __builtin_amdgcn_s_barrier();                                               \
      asm volatile("s_waitcnt lgkmcnt(0)" ::: "memory"); }

template <int F16>
__global__ __launch_bounds__(512, 2) void gemm_kernel(
    const unsigned short* __restrict__ Ah, const unsigned short* __restrict__ Al,
    const unsigned short* __restrict__ Bh, const unsigned short* __restrict__ Bl,
    const float* __restrict__ cbq, float* __restrict__ outf,
    unsigned short* __restrict__ p16, float* __restrict__ max_part,
    float* __restrict__ sum_part) {
    __shared__ __align__(16) unsigned short lds[2][2][2][8192];  // 128 KiB

    const int t = threadIdx.x;
    const int lane = t & 63;
    const int w = t >> 6;
    const int wm = w >> 2, wn = w & 3;  // 2 x 4 waves, each owns 128x64 output
    const int fr = lane & 15, fg = lane >> 4;

    int bid = blockIdx.x;
    int swz = (bid & 7) * 512 + (bid >> 3);  // 4096 % 8 == 0 -> bijective
    const int bm = swz >> 5, bn = swz & 31;
    const int row0 = bm * 256, col0 = bn * 256;
    const size_t arow0 = (size_t)row0 * 512;
    const size_t brow0 = (size_t)col0 * 512;

    // read-side: phys 16B-slot = row*4 + (col ^ ((row>>2)&3)); row bases are
    // multiples of 16 so the XOR term is lane-constant:
    const int xsl = fg ^ ((fr >> 2) & 3);
    const int a_slot = (wm * 128 + fr) * 4 + xsl;  // + (mq*4+m)*64
    const int b_slot = (wn * 64 + fr) * 4 + xsl;   // + n*64

    // staging: thread t, load j covers phys slot s = j*512 + t of a [256][32] unit
    int goff[2], sl8[2];
#pragma unroll
    for (int j = 0; j < 2; ++j) {
        int s = j * 512 + t;
        int r_ = s >> 2, cp_ = s & 3;
        int cl_ = cp_ ^ ((r_ >> 2) & 3);
        goff[j] = r_ * 512 + cl_ * 8;
        sl8[j] = s * 8;
    }

    f32x4 acc[8][4] = {};
    bf16x8 afr[4], bfr[4];

    // prologue: stage tile 0 (A-kk0, B-kk0, A-kk1, B-kk1) into buf 0
    ST(0, 0, 0, 0);
    ST(1, 0, 0, 0);
    ST(0, 1, 0, 0);
    ST(1, 1, 0, 0);
    asm volatile("s_waitcnt vmcnt(4)\n\ts_barrier" ::: "memory");  // kk0 units landed (all waves)

    for (int tt = 0; tt < 24; ++tt) {
        const int cur = tt & 1, nb = cur ^ 1;
        const bool pf = (tt < 23);
        // ---- phase 0: kk0, m0-3 ----
        RD_B(0, cur);
        RD_A(0, 0, cur);
        if (pf) ST(0, 0, nb, tt + 1);
        MIDSYNC();
        __builtin_amdgcn_s_setprio(1); MM(0); __builtin_amdgcn_s_setprio(0);
        __builtin_amdgcn_s_barrier();
        // ---- phase 1: kk0, m4-7 (B regs reused) ----
        RD_A(1, 0, cur);
        if (pf) ST(1, 0, nb, tt + 1);
        MIDSYNC();
        __builtin_amdgcn_s_setprio(1); MM(1); __builtin_amdgcn_s_setprio(0);
        if (pf) {  // kk1 units of tile tt landed (collective via barrier; fence via clobber)
            asm volatile("s_waitcnt vmcnt(4)\n\ts_barrier" ::: "memory");
        } else {
            asm volatile("s_waitcnt vmcnt(0)\n\ts_barrier" ::: "memory");
        }
        // ---- phase 2: kk1, m0-3 ----
        RD_B(1, cur);
        RD_A(0, 1, cur);
        if (pf) ST(0, 1, nb, tt + 1);
        MIDSYNC();
        __builtin_amdgcn_s_setprio(1); MM(0); __builtin_amdgcn_s_setprio(0);
        __builtin_amdgcn_s_barrier();
        // ---- phase 3: kk1, m4-7 ----
        RD_A(1, 1, cur);
        if (pf) ST(1, 1, nb, tt + 1);
        MIDSYNC();
        __builtin_amdgcn_s_setprio(1); MM(1); __builtin_amdgcn_s_setprio(0);
        if (pf) {  // kk0 units of tile tt+1 landed
            asm volatile("s_waitcnt vmcnt(4)\n\ts_barrier" ::: "memory");
        } else {
            __builtin_amdgcn_s_barrier();
        }
    }

    // ---- epilogue ----
    float* redm = (float*)&lds[0][0][0][0];  // reuse LDS after loop
    float* reds = redm + 1024;

    float cq[4];
#pragma unroll
    for (int n = 0; n < 4; ++n) cq[n] = cbq[col0 + wn * 64 + n * 16 + fr];
#pragma unroll
    for (int m = 0; m < 8; ++m)
#pragma unroll
        for (int n = 0; n < 4; ++n)
#pragma unroll
            for (int r = 0; r < 4; ++r)
                acc[m][n][r] = 2.0f * acc[m][n][r] - cq[n];

    float rmx[8][4];
#pragma unroll
    for (int m = 0; m < 8; ++m)
#pragma unroll
        for (int r = 0; r < 4; ++r) {
            float v = fmaxf(fmaxf(acc[m][0][r], acc[m][1][r]),
                            fmaxf(acc[m][2][r], acc[m][3][r]));
#pragma unroll
            for (int o = 1; o < 16; o <<= 1) v = fmaxf(v, __shfl_xor(v, o));
            rmx[m][r] = v;
        }
    __syncthreads();  // all waves out of the K-loop before LDS reuse
    if (fr == 0) {
#pragma unroll
        for (int m = 0; m < 8; ++m)
#pragma unroll
            for (int r = 0; r < 4; ++r)
                redm[wn * 256 + wm * 128 + m * 16 + fg * 4 + r] = rmx[m][r];
    }
    __syncthreads();
#pragma unroll
    for (int m = 0; m < 8; ++m)
#pragma unroll
        for (int r = 0; r < 4; ++r) {
            int row = wm * 128 + m * 16 + fg * 4 + r;
            rmx[m][r] = fmaxf(fmaxf(redm[row], redm[256 + row]),
                              fmaxf(redm[512 + row], redm[768 + row]));
        }
#pragma unroll
    for (int m = 0; m < 8; ++m)
#pragma unroll
        for (int r = 0; r < 4; ++r) {
            float s = 0.f;
#pragma unroll
            for (int n = 0; n < 4; ++n) s += __expf(acc[m][n][r] - rmx[m][r]);
#pragma unroll
            for (int o = 1; o < 16; o <<= 1) s += __shfl_xor(s, o);
            if (fr == 0) reds[wn * 256 + wm * 128 + m * 16 + fg * 4 + r] = s;
        }
    __syncthreads();
    if (wn == 0 && fr == 0) {
#pragma unroll
        for (int m = 0; m < 8; ++m)
#pragma unroll
            for (int r = 0; r < 4; ++r) {
                int row = wm * 128 + m * 16 + fg * 4 + r;
                size_t gr = (size_t)(row0 + row);
                max_part[gr * 32 + bn] = rmx[m][r];
                sum_part[gr * 32 + bn] =
                    reds[row] + reds[256 + row] + reds[512 + row] + reds[768 + row];
            }
    }
#pragma unroll
    for (int m = 0; m < 8; ++m)
#pragma unroll
        for (int n = 0; n < 4; ++n)
#pragma unroll
            for (int r = 0; r < 4; ++r) {
                size_t gr = (size_t)(row0 + wm * 128 + m * 16 + fg * 4 + r);
                size_t gi = gr * 8192 + col0 + wn * 64 + n * 16 + fr;
                if constexpr (F16) {
                    union { _Float16 h; unsigned short u; } cv;
                    cv.h = (_Float16)__expf(acc[m][n][r] - rmx[m][r]);
                    p16[gi] = cv.u;
                } else {
                    outf[gi] = acc[m][n][r];
                }
            }
}

// ---------------- combine partials over 32 col-blocks per row ----------------
__global__ void combine_kernel(const float* __restrict__ max_part,
                               const float* __restrict__ sum_part,
                               float* __restrict__ row_m, float* __restrict__ row_is,
                               float* __restrict__ scale, int do_scale) {
    int row = blockIdx.x * 8 + (threadIdx.x >> 5);
    int l = threadIdx.x & 31;
    size_t off = (size_t)row * 32 + l;
    float m = max_part[off];
    float s = sum_part[off];
    float gm = m;
#pragma unroll
    for (int o = 16; o >= 1; o >>= 1) gm = fmaxf(gm, __shfl_xor(gm, o, 32));
    float c = s * __expf(m - gm);
#pragma unroll
    for (int o = 16; o >= 1; o >>= 1) c += __shfl_xor(c, o, 32);
    float inv = 1.0f / c;
    if (do_scale) scale[off] = __expf(m - gm) * inv;
    if (l == 0) {
        row_m[row] = gm;
        row_is[row] = inv;
    }
}

// ---------------- normalize: f32-logit path ----------------
__global__ void norm_kernel(float* __restrict__ out, const float* __restrict__ row_m,
                            const float* __restrict__ row_is) {
    size_t i = (size_t)blockIdx.x * blockDim.x + threadIdx.x;
    size_t stride = (size_t)gridDim.x * blockDim.x;
    const size_t n4 = 268435456ull / 4;
    float4* p = reinterpret_cast<float4*>(out);
    for (; i < n4; i += stride) {
        int row = (int)(i >> 11);
        float m = row_m[row];
        float is = row_is[row];
        float4 v = p[i];
        v.x = __expf(v.x - m) * is;
        v.y = __expf(v.y - m) * is;
        v.z = __expf(v.z - m) * is;
        v.w = __expf(v.w - m) * is;
        p[i] = v;
    }
}

// ---------------- normalize: f16-exp path ----------------
__global__ void norm_f16_kernel(const unsigned short* __restrict__ p16,
                                const float* __restrict__ scale,
                                float* __restrict__ out) {
    size_t i = (size_t)blockIdx.x * blockDim.x + threadIdx.x;  // 8-elem group id
    size_t stride = (size_t)gridDim.x * blockDim.x;
    const size_t ng = 268435456ull / 8;
    const uint4* src = reinterpret_cast<const uint4*>(p16);
    float4* dst = reinterpret_cast<float4*>(out);
    for (; i < ng; i += stride) {
        int row = (int)(i >> 10);        // 1024 groups per row
        int bn = (int)((i >> 5) & 31);   // 32 groups per 256-col block
        float s = scale[(size_t)row * 32 + bn];
        union { uint4 u; _Float16 h[8]; } cv;
        cv.u = src[i];
        float4 o1, o2;
        o1.x = (float)cv.h[0] * s; o1.y = (float)cv.h[1] * s;
        o1.z = (float)cv.h[2] * s; o1.w = (float)cv.h[3] * s;
        o2.x = (float)cv.h[4] * s; o2.y = (float)cv.h[5] * s;
        o2.z = (float)cv.h[6] * s; o2.w = (float)cv.h[7] * s;
        dst[i * 2] = o1;
        dst[i * 2 + 1] = o2;
    }
}

extern "C" void kernel_launch(void* const* d_in, const int* in_sizes, int n_in,
                              void* d_out, int out_size, void* d_ws, size_t ws_size,
                              hipStream_t stream) {
    const float* x = (const float*)d_in[0];   // [32768,512]
    const float* cb = (const float*)d_in[1];  // [8192,512]
    float* out = (float*)d_out;               // [32768,8192]
    char* ws = (char*)d_ws;

    unsigned short* Xh = (unsigned short*)(ws);                 // 33,554,432
    unsigned short* Xl = (unsigned short*)(ws + 33554432ull);   // 33,554,432
    unsigned short* Ch = (unsigned short*)(ws + 67108864ull);   // 8,388,608
    unsigned short* Cl = (unsigned short*)(ws + 75497472ull);   // 8,388,608
    float* cbq       = (float*)(ws + 83886080ull);              // 32,768
    float* max_part  = (float*)(ws + 83918848ull);              // 4,194,304
    float* sum_part  = (float*)(ws + 88113152ull);              // 4,194,304
    float* row_m     = (float*)(ws + 92307456ull);              // 131,072
    float* row_is    = (float*)(ws + 92438528ull);              // 131,072
    float* scale     = (float*)(ws + 92569600ull);              // 4,194,304
    unsigned short* p16 = (unsigned short*)(ws + 96763904ull);  // 536,870,912 -> 633,634,816

    const bool f16path = (ws_size >= 633634816ull);

    split_kernel<<<2048, 256, 0, stream>>>(x, Xh, Xl, 32768 * 512 / 4);
    split_kernel<<<1024, 256, 0, stream>>>(cb, Ch, Cl, 8192 * 512 / 4);
    rowsq_kernel<<<2048, 256, 0, stream>>>(cb, cbq);
    if (f16path) {
        gemm_kernel<1><<<4096, 512, 0, stream>>>(Xh, Xl, Ch, Cl, cbq, out, p16,
                                                 max_part, sum_part);
        combine_kernel<<<4096, 256, 0, stream>>>(max_part, sum_part, row_m, row_is,
                                                 scale, 1);
        norm_f16_kernel<<<4096, 256, 0, stream>>>(p16, scale, out);
    } else {
        gemm_kernel<0><<<4096, 512, 0, stream>>>(Xh, Xl, Ch, Cl, cbq, out, p16,
                                                 max_part, sum_part);
        combine_kernel<<<4096, 256, 0, stream>>>(max_part, sum_part, row_m, row_is,
                                                 scale, 0);
        norm_kernel<<<4096, 256, 0, stream>>>(out, row_m, row_is);
    }
}

// Round 7
// 1380.233 us; speedup vs baseline: 1.1606x; 1.0188x over previous
//
#include <hip/hip_runtime.h>

// out[n,k] = softmax_k( 2*x_n.c_k - ||c_k||^2 )   (x_sqr cancels in softmax)
// 3-product bf16 split GEMM (logical K = 3*512 = 1536), 256x256 tiles,
// 4 phases/K-tile, k-slice stage units, counted vmcnt(4) fused into asm
// barriers. Swizzle r7: 16B-slot col c_phys = c_log ^ ((row>>1)&3)
// -> all-8-distinct bank groups per 8-lane group (was (row>>2)&3: 4-way).

typedef __attribute__((ext_vector_type(8))) __bf16 bf16x8;
typedef __attribute__((ext_vector_type(4))) float f32x4;

typedef __attribute__((address_space(1))) const void global_cvoid;
typedef __attribute__((address_space(3))) void lds_void;

__device__ inline unsigned short f32_to_bf16_rne(float f) {
    unsigned int u = __float_as_uint(f);
    unsigned int r = u + 0x7FFFu + ((u >> 16) & 1u);
    return (unsigned short)(r >> 16);
}
__device__ inline float bf16u_to_f32(unsigned short h) {
    return __uint_as_float(((unsigned int)h) << 16);
}

// ---------------- prep: fp32 -> bf16 hi/lo split ----------------
__global__ void split_kernel(const float* __restrict__ in,
                             unsigned short* __restrict__ hi,
                             unsigned short* __restrict__ lo, int n4) {
    int i = blockIdx.x * blockDim.x + threadIdx.x;
    int stride = gridDim.x * blockDim.x;
    for (; i < n4; i += stride) {
        float4 v = reinterpret_cast<const float4*>(in)[i];
        float vv[4] = {v.x, v.y, v.z, v.w};
        ushort4 hv, lv;
        unsigned short h[4], l[4];
#pragma unroll
        for (int j = 0; j < 4; ++j) {
            h[j] = f32_to_bf16_rne(vv[j]);
            float r = vv[j] - bf16u_to_f32(h[j]);
            l[j] = f32_to_bf16_rne(r);
        }
        hv.x = h[0]; hv.y = h[1]; hv.z = h[2]; hv.w = h[3];
        lv.x = l[0]; lv.y = l[1]; lv.z = l[2]; lv.w = l[3];
        reinterpret_cast<ushort4*>(hi)[i] = hv;
        reinterpret_cast<ushort4*>(lo)[i] = lv;
    }
}

// ---------------- prep: codebook row squared norms ----------------
__global__ void rowsq_kernel(const float* __restrict__ cb, float* __restrict__ out) {
    int row = blockIdx.x * 4 + (threadIdx.x >> 6);
    int lane = threadIdx.x & 63;
    const float4* p = reinterpret_cast<const float4*>(cb + (size_t)row * 512);
    float4 a = p[lane];
    float4 b = p[lane + 64];
    float s = a.x * a.x + a.y * a.y + a.z * a.z + a.w * a.w +
              b.x * b.x + b.y * b.y + b.z * b.z + b.w * b.w;
#pragma unroll
    for (int o = 32; o >= 1; o >>= 1) s += __shfl_xor(s, o);
    if (lane == 0) out[row] = s;
}

// ---------------- GEMM 256x256 ----------------
// Grid 4096 (128 bm x 32 bn, bijective XCD swizzle), 512 threads = 8 waves (2x4).
// LDS: lds[buf][mat A/B][kk][256 rows x 32 k bf16] = 128 KiB. 24 K-tiles of BK=64.

#define RD_A(mq_, kk_, b_)                                                        \
    { _Pragma("unroll") for (int m = 0; m < 4; ++m)                               \
        afr[m] = *(const bf16x8*)&lds[b_][0][kk_][(a_slot + ((mq_)*4 + m) * 64) * 8]; }

#define RD_B(kk_, b_)                                                             \
    { _Pragma("unroll") for (int n = 0; n < 4; ++n)                               \
        bfr[n] = *(const bf16x8*)&lds[b_][1][kk_][(b_slot + n * 64) * 8]; }

#define ST(mat_, kk_, b_, tt_)                                                    \
    { int prod_ = (tt_) >> 3, ch_ = (tt_) & 7;                                    \
      const unsigned short* bse_;                                                 \
      if ((mat_) == 0) bse_ = (prod_ < 2 ? Ah : Al) + arow0;                      \
      else             bse_ = (prod_ == 1 ? Bl : Bh) + brow0;                     \
      bse_ += ch_ * 64 + (kk_) * 32;                                              \
      _Pragma("unroll") for (int j = 0; j < 2; ++j)                               \
          __builtin_amdgcn_global_load_lds((global_cvoid*)(bse_ + goff[j]),       \
              (lds_void*)&lds[b_][mat_][kk_][sl8[j]], 16, 0, 0);                  \
    }

#define MM(mq_)                                                                   \
    { _Pragma("unroll") for (int m = 0; m < 4; ++m)                               \
      _Pragma("unroll") for (int n = 0; n < 4; ++n)                               \
          acc[(mq_) * 4 + m][n] = __builtin_amdgcn_mfma_f32_16x16x32_bf16(        \
              afr[m], bfr[n], acc[(mq_) * 4 + m][n], 0, 0, 0); }

#define MIDSYNC()                                                                 \
    { __builtin_amdgcn_s_barrier();                                               \
      asm volatile("s_waitcnt lgkmcnt(0)" ::: "memory"); }

template <int F16>
__global__ __launch_bounds__(512, 2) void gemm_kernel(
    const unsigned short* __restrict__ Ah, const unsigned short* __restrict__ Al,
    const unsigned short* __restrict__ Bh, const unsigned short* __restrict__ Bl,
    const float* __restrict__ cbq, float* __restrict__ outf,
    unsigned short* __restrict__ p16, float* __restrict__ max_part,
    float* __restrict__ sum_part) {
    __shared__ __align__(16) unsigned short lds[2][2][2][8192];  // 128 KiB

    const int t = threadIdx.x;
    const int lane = t & 63;
    const int w = t >> 6;
    const int wm = w >> 2, wn = w & 3;  // 2 x 4 waves, each owns 128x64 output
    const int fr = lane & 15, fg = lane >> 4;

    int bid = blockIdx.x;
    int swz = (bid & 7) * 512 + (bid >> 3);  // 4096 % 8 == 0 -> bijective
    const int bm = swz >> 5, bn = swz & 31;
    const int row0 = bm * 256, col0 = bn * 256;
    const size_t arow0 = (size_t)row0 * 512;
    const size_t brow0 = (size_t)col0 * 512;

    // read-side: phys 16B-slot = row*4 + (col ^ ((row>>1)&3)); fragment row
    // bases are multiples of 16 so the XOR term is lane-constant in fr:
    const int xsl = fg ^ ((fr >> 1) & 3);
    const int a_slot = (wm * 128 + fr) * 4 + xsl;  // + (mq*4+m)*64
    const int b_slot = (wn * 64 + fr) * 4 + xsl;   // + n*64

    // staging: thread t, load j covers phys slot s = j*512 + t of a [256][32] unit
    int goff[2], sl8[2];
#pragma unroll
    for (int j = 0; j < 2; ++j) {
        int s = j * 512 + t;
        int r_ = s >> 2, cp_ = s & 3;
        int cl_ = cp_ ^ ((r_ >> 1) & 3);   // inverse of read-side XOR
        goff[j] = r_ * 512 + cl_ * 8;
        sl8[j] = s * 8;
    }

    f32x4 acc[8][4] = {};
    bf16x8 afr[4], bfr[4];

    // prologue: stage tile 0 (A-kk0, B-kk0, A-kk1, B-kk1) into buf 0
    ST(0, 0, 0, 0);
    ST(1, 0, 0, 0);
    ST(0, 1, 0, 0);
    ST(1, 1, 0, 0);
    asm volatile("s_waitcnt vmcnt(4)\n\ts_barrier" ::: "memory");  // kk0 units landed

    for (int tt = 0; tt < 24; ++tt) {
        const int cur = tt & 1, nb = cur ^ 1;
        const bool pf = (tt < 23);
        // ---- phase 0: kk0, m0-3 ----
        RD_B(0, cur);
        RD_A(0, 0, cur);
        if (pf) ST(0, 0, nb, tt + 1);
        MIDSYNC();
        __builtin_amdgcn_s_setprio(1); MM(0); __builtin_amdgcn_s_setprio(0);
        __builtin_amdgcn_s_barrier();
        // ---- phase 1: kk0, m4-7 (B regs reused) ----
        RD_A(1, 0, cur);
        if (pf) ST(1, 0, nb, tt + 1);
        MIDSYNC();
        __builtin_amdgcn_s_setprio(1); MM(1); __builtin_amdgcn_s_setprio(0);
        if (pf) {  // kk1 units of tile tt landed (collective via barrier)
            asm volatile("s_waitcnt vmcnt(4)\n\ts_barrier" ::: "memory");
        } else {
            asm volatile("s_waitcnt vmcnt(0)\n\ts_barrier" ::: "memory");
        }
        // ---- phase 2: kk1, m0-3 ----
        RD_B(1, cur);
        RD_A(0, 1, cur);
        if (pf) ST(0, 1, nb, tt + 1);
        MIDSYNC();
        __builtin_amdgcn_s_setprio(1); MM(0); __builtin_amdgcn_s_setprio(0);
        __builtin_amdgcn_s_barrier();
        // ---- phase 3: kk1, m4-7 ----
        RD_A(1, 1, cur);
        if (pf) ST(1, 1, nb, tt + 1);
        MIDSYNC();
        __builtin_amdgcn_s_setprio(1); MM(1); __builtin_amdgcn_s_setprio(0);
        if (pf) {  // kk0 units of tile tt+1 landed
            asm volatile("s_waitcnt vmcnt(4)\n\ts_barrier" ::: "memory");
        } else {
            __builtin_amdgcn_s_barrier();
        }
    }

    // ---- epilogue ----
    float* redm = (float*)&lds[0][0][0][0];  // reuse LDS after loop
    float* reds = redm + 1024;

    float cq[4];
#pragma unroll
    for (int n = 0; n < 4; ++n) cq[n] = cbq[col0 + wn * 64 + n * 16 + fr];
#pragma unroll
    for (int m = 0; m < 8; ++m)
#pragma unroll
        for (int n = 0; n < 4; ++n)
#pragma unroll
            for (int r = 0; r < 4; ++r)
                acc[m][n][r] = 2.0f * acc[m][n][r] - cq[n];

    float rmx[8][4];
#pragma unroll
    for (int m = 0; m < 8; ++m)
#pragma unroll
        for (int r = 0; r < 4; ++r) {
            float v = fmaxf(fmaxf(acc[m][0][r], acc[m][1][r]),
                            fmaxf(acc[m][2][r], acc[m][3][r]));
#pragma unroll
            for (int o = 1; o < 16; o <<= 1) v = fmaxf(v, __shfl_xor(v, o));
            rmx[m][r] = v;
        }
    __syncthreads();  // all waves out of the K-loop before LDS reuse
    if (fr == 0) {
#pragma unroll
        for (int m = 0; m < 8; ++m)
#pragma unroll
            for (int r = 0; r < 4; ++r)
                redm[wn * 256 + wm * 128 + m * 16 + fg * 4 + r] = rmx[m][r];
    }
    __syncthreads();
#pragma unroll
    for (int m = 0; m < 8; ++m)
#pragma unroll
        for (int r = 0; r < 4; ++r) {
            int row = wm * 128 + m * 16 + fg * 4 + r;
            rmx[m][r] = fmaxf(fmaxf(redm[row], redm[256 + row]),
                              fmaxf(redm[512 + row], redm[768 + row]));
        }
#pragma unroll
    for (int m = 0; m < 8; ++m)
#pragma unroll
        for (int r = 0; r < 4; ++r) {
            float s = 0.f;
#pragma unroll
            for (int n = 0; n < 4; ++n) s += __expf(acc[m][n][r] - rmx[m][r]);
#pragma unroll
            for (int o = 1; o < 16; o <<= 1) s += __shfl_xor(s, o);
            if (fr == 0) reds[wn * 256 + wm * 128 + m * 16 + fg * 4 + r] = s;
        }
    __syncthreads();
    if (wn == 0 && fr == 0) {
#pragma unroll
        for (int m = 0; m < 8; ++m)
#pragma unroll
            for (int r = 0; r < 4; ++r) {
                int row = wm * 128 + m * 16 + fg * 4 + r;
                size_t gr = (size_t)(row0 + row);
                max_part[gr * 32 + bn] = rmx[m][r];
                sum_part[gr * 32 + bn] =
                    reds[row] + reds[256 + row] + reds[512 + row] + reds[768 + row];
            }
    }
#pragma unroll
    for (int m = 0; m < 8; ++m)
#pragma unroll
        for (int n = 0; n < 4; ++n)
#pragma unroll
            for (int r = 0; r < 4; ++r) {
                size_t gr = (size_t)(row0 + wm * 128 + m * 16 + fg * 4 + r);
                size_t gi = gr * 8192 + col0 + wn * 64 + n * 16 + fr;
                if constexpr (F16) {
                    union { _Float16 h; unsigned short u; } cv;
                    cv.h = (_Float16)__expf(acc[m][n][r] - rmx[m][r]);
                    p16[gi] = cv.u;
                } else {
                    outf[gi] = acc[m][n][r];
                }
            }
}

// ---------------- combine partials over 32 col-blocks per row ----------------
__global__ void combine_kernel(const float* __restrict__ max_part,
                               const float* __restrict__ sum_part,
                               float* __restrict__ row_m, float* __restrict__ row_is,
                               float* __restrict__ scale, int do_scale) {
    int row = blockIdx.x * 8 + (threadIdx.x >> 5);
    int l = threadIdx.x & 31;
    size_t off = (size_t)row * 32 + l;
    float m = max_part[off];
    float s = sum_part[off];
    float gm = m;
#pragma unroll
    for (int o = 16; o >= 1; o >>= 1) gm = fmaxf(gm, __shfl_xor(gm, o, 32));
    float c = s * __expf(m - gm);
#pragma unroll
    for (int o = 16; o >= 1; o >>= 1) c += __shfl_xor(c, o, 32);
    float inv = 1.0f / c;
    if (do_scale) scale[off] = __expf(m - gm) * inv;
    if (l == 0) {
        row_m[row] = gm;
        row_is[row] = inv;
    }
}

// ---------------- normalize: f32-logit path ----------------
__global__ void norm_kernel(float* __restrict__ out, const float* __restrict__ row_m,
                            const float* __restrict__ row_is) {
    size_t i = (size_t)blockIdx.x * blockDim.x + threadIdx.x;
    size_t stride = (size_t)gridDim.x * blockDim.x;
    const size_t n4 = 268435456ull / 4;
    float4* p = reinterpret_cast<float4*>(out);
    for (; i < n4; i += stride) {
        int row = (int)(i >> 11);
        float m = row_m[row];
        float is = row_is[row];
        float4 v = p[i];
        v.x = __expf(v.x - m) * is;
        v.y = __expf(v.y - m) * is;
        v.z = __expf(v.z - m) * is;
        v.w = __expf(v.w - m) * is;
        p[i] = v;
    }
}

// ---------------- normalize: f16-exp path ----------------
__global__ void norm_f16_kernel(const unsigned short* __restrict__ p16,
                                const float* __restrict__ scale,
                                float* __restrict__ out) {
    size_t i = (size_t)blockIdx.x * blockDim.x + threadIdx.x;  // 8-elem group id
    size_t stride = (size_t)gridDim.x * blockDim.x;
    const size_t ng = 268435456ull / 8;
    const uint4* src = reinterpret_cast<const uint4*>(p16);
    float4* dst = reinterpret_cast<float4*>(out);
    for (; i < ng; i += stride) {
        int row = (int)(i >> 10);        // 1024 groups per row
        int bn = (int)((i >> 5) & 31);   // 32 groups per 256-col block
        float s = scale[(size_t)row * 32 + bn];
        union { uint4 u; _Float16 h[8]; } cv;
        cv.u = src[i];
        float4 o1, o2;
        o1.x = (float)cv.h[0] * s; o1.y = (float)cv.h[1] * s;
        o1.z = (float)cv.h[2] * s; o1.w = (float)cv.h[3] * s;
        o2.x = (float)cv.h[4] * s; o2.y = (float)cv.h[5] * s;
        o2.z = (float)cv.h[6] * s; o2.w = (float)cv.h[7] * s;
        dst[i * 2] = o1;
        dst[i * 2 + 1] = o2;
    }
}

extern "C" void kernel_launch(void* const* d_in, const int* in_sizes, int n_in,
                              void* d_out, int out_size, void* d_ws, size_t ws_size,
                              hipStream_t stream) {
    const float* x = (const float*)d_in[0];   // [32768,512]
    const float* cb = (const float*)d_in[1];  // [8192,512]
    float* out = (float*)d_out;               // [32768,8192]
    char* ws = (char*)d_ws;

    unsigned short* Xh = (unsigned short*)(ws);                 // 33,554,432
    unsigned short* Xl = (unsigned short*)(ws + 33554432ull);   // 33,554,432
    unsigned short* Ch = (unsigned short*)(ws + 67108864ull);   // 8,388,608
    unsigned short* Cl = (unsigned short*)(ws + 75497472ull);   // 8,388,608
    float* cbq       = (float*)(ws + 83886080ull);              // 32,768
    float* max_part  = (float*)(ws + 83918848ull);              // 4,194,304
    float* sum_part  = (float*)(ws + 88113152ull);              // 4,194,304
    float* row_m     = (float*)(ws + 92307456ull);              // 131,072
    float* row_is    = (float*)(ws + 92438528ull);              // 131,072
    float* scale     = (float*)(ws + 92569600ull);              // 4,194,304
    unsigned short* p16 = (unsigned short*)(ws + 96763904ull);  // 536,870,912 -> 633,634,816

    const bool f16path = (ws_size >= 633634816ull);

    split_kernel<<<2048, 256, 0, stream>>>(x, Xh, Xl, 32768 * 512 / 4);
    split_kernel<<<1024, 256, 0, stream>>>(cb, Ch, Cl, 8192 * 512 / 4);
    rowsq_kernel<<<2048, 256, 0, stream>>>(cb, cbq);
    if (f16path) {
        gemm_kernel<1><<<4096, 512, 0, stream>>>(Xh, Xl, Ch, Cl, cbq, out, p16,
                                                 max_part, sum_part);
        combine_kernel<<<4096, 256, 0, stream>>>(max_part, sum_part, row_m, row_is,
                                                 scale, 1);
        norm_f16_kernel<<<4096, 256, 0, stream>>>(p16, scale, out);
    } else {
        gemm_kernel<0><<<4096, 512, 0, stream>>>(Xh, Xl, Ch, Cl, cbq, out, p16,
                                                 max_part, sum_part);
        combine_kernel<<<4096, 256, 0, stream>>>(max_part, sum_part, row_m, row_is,
                                                 scale, 0);
        norm_kernel<<<4096, 256, 0, stream>>>(out, row_m, row_is);
    }
}